// Round 4
// baseline (230.938 us; speedup 1.0000x reference)
//
#include <hip/hip_runtime.h>
#include <cmath>

typedef _Float16 half8 __attribute__((ext_vector_type(8)));
typedef float f32x4 __attribute__((ext_vector_type(4)));

#define GLD_LDS16(gptr, lptr)                                                  \
  __builtin_amdgcn_global_load_lds(                                            \
      (const __attribute__((address_space(1))) void*)(gptr),                   \
      (__attribute__((address_space(3))) void*)(lptr), 16, 0, 0)

#define MEMFENCE asm volatile("" ::: "memory")

// ---------------- merged f32 -> f16 conversion (one dispatch) ---------------
// Each block converts exactly 2048 elements (256 thr x 8). All sizes are
// multiples of 2048. Ranges: [x | W_embed | W_layers | W_head].
__global__ void cvt_all(const float* __restrict__ s0, const float* __restrict__ s1,
                        const float* __restrict__ s2, const float* __restrict__ s3,
                        _Float16* __restrict__ d0, _Float16* __restrict__ d1,
                        _Float16* __restrict__ d2, _Float16* __restrict__ d3,
                        long nb0, long nb1, long nb2) {
  long b = blockIdx.x;
  const float* s;
  _Float16* d;
  if (b < nb0) {
    s = s0; d = d0;
  } else if (b < nb0 + nb1) {
    s = s1; d = d1; b -= nb0;
  } else if (b < nb0 + nb1 + nb2) {
    s = s2; d = d2; b -= nb0 + nb1;
  } else {
    s = s3; d = d3; b -= nb0 + nb1 + nb2;
  }
  long i = b * 2048 + (long)threadIdx.x * 8;
  const float4* p = (const float4*)(s + i);
  float4 a = p[0];
  float4 c = p[1];
  half8 h = {(_Float16)a.x, (_Float16)a.y, (_Float16)a.z, (_Float16)a.w,
             (_Float16)c.x, (_Float16)c.y, (_Float16)c.z, (_Float16)c.w};
  *(half8*)(d + i) = h;
}

// ---------------- GEMM: C[m,n] = sum_k A[m,k]*B[n,k]  (both K-major) --------
// EPI: 0 = acc+bias -> f16 ; 1 = 0.5*tanh(acc+bias) -> f16 ; 2 = acc+bias -> f32
// NW:  B-fragments per wave. BN = NW*32 (4 -> BN=128, 2 -> BN=64).
// BM=256, BK=64, 512 threads = 8 waves (4M x 2N), wave tile 64 x (BN/2).
// Schedule (counted-vmcnt, 2 barriers/K-tile):
//   top:  stage(t+1) [4+BLOADS issues] ; vmcnt(4+BLOADS) waits tile t only
//         (t+1's loads stay in flight across the whole K-tile) ; s_barrier
//   body: reads kk0 -> MFMA kk0 -> reads kk1 -> MFMA kk1 (same buffer, no
//         barriers needed; compiler interleaves via fine lgkmcnt)
//   end:  s_barrier (all reads of buf[cur] retired -> next iter may overwrite)
// T2 XOR swizzle (chunk ^ row&7) on pre-swizzled global source + ds_read.
// Grid: 256 blocks = 16x16 tiles; 2-D XCD rects (4 tile-rows x 8 tile-cols
// per XCD) so the per-K-slice working set (~256 KB) L2-hits across the rect.
template <int EPI, int NW>
__global__ __launch_bounds__(512, 2) void gemmk(
    const _Float16* __restrict__ A, const _Float16* __restrict__ Bm,
    const float* __restrict__ bias, void* __restrict__ Cout, int N, int K) {
  constexpr int BN = NW * 32;
  constexpr int BLOADS = BN / 64;  // 64-row staging issues for B (2 or 1)
  __shared__ _Float16 As[2][256 * 64];
  __shared__ _Float16 Bs[2][BN * 64];

  const int tid = threadIdx.x;
  const int lane = tid & 63;
  const int wave = tid >> 6;

  // 2-D XCD rect mapping for a 16x16 tile grid (256 blocks):
  // xcd = bid&7 owns a 4-row x 8-col rect of tiles.
  const int bid = blockIdx.x;
  const int xcd = bid & 7;
  const int idx = bid >> 3;  // 0..31 within rect
  const int brow = ((xcd >> 1) * 4 + (idx & 3)) * 256;
  const int bcol = ((xcd & 1) * 8 + (idx >> 2)) * BN;

  const int wr = (wave >> 1) * 64;        // 4 M-waves
  const int wc = (wave & 1) * (BN / 2);   // 2 N-waves

  // staging: 512 thr x 16B covers 64 rows x 64 f16 cols per issue.
  const int sr = tid >> 3;
  const int sc = ((tid & 7) ^ (sr & 7)) * 8;  // T2: pre-swizzled source col
  const _Float16* Ag = A + (size_t)(brow + sr) * K + sc;
  const _Float16* Bg = Bm + (size_t)(bcol + sr) * K + sc;
  const int ldst = tid * 8;  // linear LDS dest (required by global_load_lds)

  // MFMA fragment geometry (16x16x32): row=lane&15, k-half=(lane>>4)*8
  const int frow = lane & 15;
  const int hi = lane >> 4;
  const int xr = lane & 7;  // read-side XOR (matches source swizzle)

  // hoisted LDS read offsets (element units)
  int aoff[4], boff[NW];
#pragma unroll
  for (int m = 0; m < 4; m++) aoff[m] = (wr + m * 16 + frow) * 64;
#pragma unroll
  for (int n = 0; n < NW; n++) boff[n] = (wc + n * 16 + frow) * 64;
  const int ch0 = (hi ^ xr) * 8;
  const int ch1 = ((4 + hi) ^ xr) * 8;

  f32x4 acc[4][NW];
#pragma unroll
  for (int m = 0; m < 4; m++)
#pragma unroll
    for (int n = 0; n < NW; n++) acc[m][n] = f32x4{0.f, 0.f, 0.f, 0.f};

  const int nt = K >> 6;

  auto stage = [&](int buf, int t) {
    const _Float16* ag = Ag + t * 64;
    const _Float16* bg = Bg + t * 64;
    _Float16* al = &As[buf][ldst];
    _Float16* bl = &Bs[buf][ldst];
#pragma unroll
    for (int i = 0; i < 4; i++)
      GLD_LDS16(ag + (size_t)i * 64 * K, al + i * 4096);
#pragma unroll
    for (int i = 0; i < BLOADS; i++)
      GLD_LDS16(bg + (size_t)i * 64 * K, bl + i * 4096);
  };

  stage(0, 0);  // prologue: tile 0 in flight

  for (int t = 0; t < nt; ++t) {
    const int cur = t & 1;
    if (t + 1 < nt) {
      stage(cur ^ 1, t + 1);  // issue next tile first (stays in flight all K-tile)
      if constexpr (NW == 4)
        asm volatile("s_waitcnt vmcnt(6)" ::: "memory");  // tile t landed
      else
        asm volatile("s_waitcnt vmcnt(5)" ::: "memory");
    } else {
      asm volatile("s_waitcnt vmcnt(0)" ::: "memory");
    }
    __builtin_amdgcn_s_barrier();
    MEMFENCE;

    const _Float16* as = &As[cur][0];
    const _Float16* bs = &Bs[cur][0];

    half8 a0[4], b0[NW];
#pragma unroll
    for (int m = 0; m < 4; m++) a0[m] = *(const half8*)(as + aoff[m] + ch0);
#pragma unroll
    for (int n = 0; n < NW; n++) b0[n] = *(const half8*)(bs + boff[n] + ch0);
    __builtin_amdgcn_s_setprio(1);
#pragma unroll
    for (int m = 0; m < 4; m++)
#pragma unroll
      for (int n = 0; n < NW; n++)
        acc[m][n] =
            __builtin_amdgcn_mfma_f32_16x16x32_f16(a0[m], b0[n], acc[m][n], 0, 0, 0);
    __builtin_amdgcn_s_setprio(0);

    half8 a1[4], b1[NW];
#pragma unroll
    for (int m = 0; m < 4; m++) a1[m] = *(const half8*)(as + aoff[m] + ch1);
#pragma unroll
    for (int n = 0; n < NW; n++) b1[n] = *(const half8*)(bs + boff[n] + ch1);
    __builtin_amdgcn_s_setprio(1);
#pragma unroll
    for (int m = 0; m < 4; m++)
#pragma unroll
      for (int n = 0; n < NW; n++)
        acc[m][n] =
            __builtin_amdgcn_mfma_f32_16x16x32_f16(a1[m], b1[n], acc[m][n], 0, 0, 0);
    __builtin_amdgcn_s_setprio(0);

    MEMFENCE;  // reads retired (consumed by MFMA) before end barrier
    __builtin_amdgcn_s_barrier();
    MEMFENCE;
  }

  // epilogue: C/D layout col = lane&15, row = (lane>>4)*4 + reg
  const int r0 = hi * 4;
  const int c0 = frow;
#pragma unroll
  for (int n = 0; n < NW; n++) {
    const int col = bcol + wc + n * 16 + c0;
    const float bv = bias[col];
#pragma unroll
    for (int m = 0; m < 4; m++) {
#pragma unroll
      for (int r = 0; r < 4; r++) {
        const int row = brow + wr + m * 16 + r0 + r;
        float v = acc[m][n][r] + bv;
        if (EPI == 1) v = 0.5f * tanhf(v);
        if (EPI == 2)
          ((float*)Cout)[(size_t)row * N + col] = v;
        else
          ((_Float16*)Cout)[(size_t)row * N + col] = (_Float16)v;
      }
    }
  }
}

// ---------------------------------------------------------------------------
extern "C" void kernel_launch(void* const* d_in, const int* in_sizes, int n_in,
                              void* d_out, int out_size, void* d_ws,
                              size_t ws_size, hipStream_t stream) {
  (void)in_sizes;
  (void)n_in;
  (void)out_size;
  (void)ws_size;

  const float* x = (const float*)d_in[0];        // [4096,1024]
  const float* W_embed = (const float*)d_in[1];  // [2048,1024]
  const float* b_embed = (const float*)d_in[2];  // [2048]
  const float* W_layers = (const float*)d_in[3]; // [3,2048,2048]
  const float* b_layers = (const float*)d_in[4]; // [3,2048]
  const float* W_head = (const float*)d_in[5];   // [1024,2048]
  const float* b_head = (const float*)d_in[6];   // [1024]

  const int B = 4096, I = 1024, H = 2048, O = 1024;

  char* w = (char*)d_ws;
  auto carve = [&](size_t bytes) {
    char* p = w;
    w += (bytes + 255) & ~(size_t)255;
    return p;
  };
  _Float16* xh = (_Float16*)carve((size_t)B * I * 2);
  _Float16* Weh = (_Float16*)carve((size_t)H * I * 2);
  _Float16* Wlh = (_Float16*)carve((size_t)3 * H * H * 2);
  _Float16* Whh = (_Float16*)carve((size_t)O * H * 2);
  _Float16* bufE = (_Float16*)carve((size_t)B * H * 2);
  _Float16* bufA = (_Float16*)carve((size_t)B * H * 2);

  // one merged conversion dispatch: x, W_embed, W_layers, W_head
  const long n0 = (long)B * I, n1 = (long)H * I, n2 = (long)3 * H * H,
             n3 = (long)O * H;
  const long nb0 = n0 / 2048, nb1 = n1 / 2048, nb2 = n2 / 2048,
             nb3 = n3 / 2048;
  cvt_all<<<(int)(nb0 + nb1 + nb2 + nb3), 256, 0, stream>>>(
      x, W_embed, W_layers, W_head, xh, Weh, Wlh, Whh, nb0, nb1, nb2);

  dim3 blk(512);
  // all grids are 16x16 tiles = 256 blocks
  // x_emb = x @ W_embed^T + b_embed            [B,H], f16
  gemmk<0, 4><<<256, blk, 0, stream>>>(xh, Weh, b_embed, bufE, H, I);
  // h0 = 0.5*tanh(x_emb @ W0^T + b0)           [B,H], f16
  gemmk<1, 4><<<256, blk, 0, stream>>>(bufE, Wlh, b_layers, bufA, H, H);
  // h1 = 0.5*tanh(h0 @ W1^T + b1)              [B,H], f16
  gemmk<1, 4><<<256, blk, 0, stream>>>(bufA, Wlh + (size_t)H * H,
                                       b_layers + H, bufE, H, H);
  // h2 = 0.5*tanh(h1 @ W2^T + b2)              [B,H], f16
  gemmk<1, 4><<<256, blk, 0, stream>>>(bufE, Wlh + (size_t)2 * H * H,
                                       b_layers + 2 * H, bufA, H, H);
  // out = h2 @ W_head^T + b_head               [B,O], f32  (BN=64)
  gemmk<2, 2><<<256, blk, 0, stream>>>(bufA, Whh, b_head, d_out, O, H);
}

// Round 5
// 226.190 us; speedup vs baseline: 1.0210x; 1.0210x over previous
//
#include <hip/hip_runtime.h>
#include <cmath>

typedef _Float16 half8 __attribute__((ext_vector_type(8)));
typedef float f32x4 __attribute__((ext_vector_type(4)));

#define GLD_LDS16(gptr, lptr)                                                  \
  __builtin_amdgcn_global_load_lds(                                            \
      (const __attribute__((address_space(1))) void*)(gptr),                   \
      (__attribute__((address_space(3))) void*)(lptr), 16, 0, 0)

#define MEMFENCE asm volatile("" ::: "memory")

// ---------------- merged f32 -> f16 conversion (one dispatch) ---------------
__global__ void cvt_all(const float* __restrict__ s0, const float* __restrict__ s1,
                        const float* __restrict__ s2, const float* __restrict__ s3,
                        _Float16* __restrict__ d0, _Float16* __restrict__ d1,
                        _Float16* __restrict__ d2, _Float16* __restrict__ d3,
                        long nb0, long nb1, long nb2) {
  long b = blockIdx.x;
  const float* s;
  _Float16* d;
  if (b < nb0) {
    s = s0; d = d0;
  } else if (b < nb0 + nb1) {
    s = s1; d = d1; b -= nb0;
  } else if (b < nb0 + nb1 + nb2) {
    s = s2; d = d2; b -= nb0 + nb1;
  } else {
    s = s3; d = d3; b -= nb0 + nb1 + nb2;
  }
  long i = b * 2048 + (long)threadIdx.x * 8;
  const float4* p = (const float4*)(s + i);
  float4 a = p[0];
  float4 c = p[1];
  half8 h = {(_Float16)a.x, (_Float16)a.y, (_Float16)a.z, (_Float16)a.w,
             (_Float16)c.x, (_Float16)c.y, (_Float16)c.z, (_Float16)c.w};
  *(half8*)(d + i) = h;
}

// ---------------- GEMM: C[m,n] = sum_k A[m,k]*B[n,k]  (both K-major) --------
// EPI: 0 = acc+bias -> f16 ; 1 = 0.5*tanh(acc+bias) -> f16 ; 2 = acc+bias -> f32
// NW:  B-fragments per wave. BN = NW*32 (4 -> BN=128, 2 -> BN=64).
// BM=128, BK=64, 512 threads = 8 waves (4M x 2N), wave tile 32 x (BN/2).
// LDS = 2dbuf x (128 + BN) x 64 f16 = 64 KB (NW=4) -> 2 blocks/CU,
// 16 waves/CU: cross-block overlap hides stage/barrier stalls (m114).
// Fine phases (r3-proven): per kk-half { ds_read frags || stage half of t+1
//   -> s_barrier -> setprio(1) MFMA setprio(0) -> s_barrier }.
// Counted wait (T4): vmcnt(2) at tile top waits only tile t's loads; t+1's
// prefetch never drained inside the loop.
// T2 XOR swizzle (chunk^row&7) via pre-swizzled global source + ds_read.
// Grid: 512 blocks = 32x16 tiles; 2-D XCD rects (8x8 tiles per XCD).
template <int EPI, int NW>
__global__ __launch_bounds__(512, 4) void gemmf(
    const _Float16* __restrict__ A, const _Float16* __restrict__ Bm,
    const float* __restrict__ bias, void* __restrict__ Cout, int N, int K) {
  constexpr int BN = NW * 32;
  constexpr int BLOADS = BN / 64;  // B staging issues (2 or 1)
  __shared__ _Float16 As[2][128 * 64];
  __shared__ _Float16 Bs[2][BN * 64];

  const int tid = threadIdx.x;
  const int lane = tid & 63;
  const int wave = tid >> 6;

  // 2-D XCD rect mapping for a 32x16 tile grid (512 blocks):
  // XCDs tiled 4 rows x 2 cols; each XCD owns an 8x8 tile rect.
  const int bid = blockIdx.x;
  const int xcd = bid & 7;
  const int idx = bid >> 3;  // 0..63
  const int brow = ((xcd >> 1) * 8 + (idx & 7)) * 128;
  const int bcol = ((xcd & 1) * 8 + (idx >> 3)) * BN;

  const int wr = (wave >> 1) * 32;        // 4 M-waves, 32 rows each
  const int wc = (wave & 1) * (BN / 2);   // 2 N-waves

  // staging: 512 thr x 16B covers 64 rows x 64 f16 cols per issue.
  const int sr = tid >> 3;
  const int sc = ((tid & 7) ^ (sr & 7)) * 8;  // T2: pre-swizzled source col
  const _Float16* Ag = A + (size_t)(brow + sr) * K + sc;
  const _Float16* Bg = Bm + (size_t)(bcol + sr) * K + sc;
  const int ldst = tid * 8;  // linear LDS dest (required by global_load_lds)

  // MFMA fragment geometry (16x16x32): row=lane&15, k-half=(lane>>4)*8
  const int frow = lane & 15;
  const int hi = lane >> 4;
  const int xr = lane & 7;  // read-side XOR (matches source swizzle)

  int aoff[2], boff[NW];
#pragma unroll
  for (int m = 0; m < 2; m++) aoff[m] = (wr + m * 16 + frow) * 64;
#pragma unroll
  for (int n = 0; n < NW; n++) boff[n] = (wc + n * 16 + frow) * 64;
  const int ch0 = (hi ^ xr) * 8;
  const int ch1 = ((4 + hi) ^ xr) * 8;

  f32x4 acc[2][NW];
#pragma unroll
  for (int m = 0; m < 2; m++)
#pragma unroll
    for (int n = 0; n < NW; n++) acc[m][n] = f32x4{0.f, 0.f, 0.f, 0.f};

  const int nt = K >> 6;

  auto stageA = [&](int buf, int t) {
    const _Float16* ag = Ag + t * 64;
    _Float16* al = &As[buf][ldst];
#pragma unroll
    for (int i = 0; i < 2; i++)
      GLD_LDS16(ag + (size_t)i * 64 * K, al + i * 4096);
  };
  auto stageB = [&](int buf, int t) {
    const _Float16* bg = Bg + t * 64;
    _Float16* bl = &Bs[buf][ldst];
#pragma unroll
    for (int i = 0; i < BLOADS; i++)
      GLD_LDS16(bg + (size_t)i * 64 * K, bl + i * 4096);
  };

  // prologue: stage tile 0 fully; drain; barrier
  stageA(0, 0);
  stageB(0, 0);
  asm volatile("s_waitcnt vmcnt(0)" ::: "memory");
  __builtin_amdgcn_s_barrier();
  MEMFENCE;

  for (int t = 0; t < nt; ++t) {
    const int cur = t & 1;
    const bool pf = (t + 1 < nt);

    // ===== phase 1 : kk = 0 ; stage A-half of t+1 ; wait tile t landed =====
    if (pf) {
      stageA(cur ^ 1, t + 1);
      // outstanding: t+1's A(2) (+ B issued last phase already retired by
      // earlier wait). Wait until only those 2 remain -> tile t fully in LDS.
      asm volatile("s_waitcnt vmcnt(2)" ::: "memory");
    } else {
      asm volatile("s_waitcnt vmcnt(0)" ::: "memory");
    }
    __builtin_amdgcn_s_barrier();  // tile t visible to all waves
    MEMFENCE;

    const _Float16* as = &As[cur][0];
    const _Float16* bs = &Bs[cur][0];

    half8 a0[2], b0[NW];
#pragma unroll
    for (int m = 0; m < 2; m++) a0[m] = *(const half8*)(as + aoff[m] + ch0);
#pragma unroll
    for (int n = 0; n < NW; n++) b0[n] = *(const half8*)(bs + boff[n] + ch0);
    MEMFENCE;
    __builtin_amdgcn_s_setprio(1);
#pragma unroll
    for (int m = 0; m < 2; m++)
#pragma unroll
      for (int n = 0; n < NW; n++)
        acc[m][n] =
            __builtin_amdgcn_mfma_f32_16x16x32_f16(a0[m], b0[n], acc[m][n], 0, 0, 0);
    __builtin_amdgcn_s_setprio(0);
    MEMFENCE;
    __builtin_amdgcn_s_barrier();
    MEMFENCE;

    // ===== phase 2 : kk = 1 ; stage B-half of t+1 =====
    if (pf) stageB(cur ^ 1, t + 1);
    half8 a1[2], b1[NW];
#pragma unroll
    for (int m = 0; m < 2; m++) a1[m] = *(const half8*)(as + aoff[m] + ch1);
#pragma unroll
    for (int n = 0; n < NW; n++) b1[n] = *(const half8*)(bs + boff[n] + ch1);
    MEMFENCE;
    __builtin_amdgcn_s_setprio(1);
#pragma unroll
    for (int m = 0; m < 2; m++)
#pragma unroll
      for (int n = 0; n < NW; n++)
        acc[m][n] =
            __builtin_amdgcn_mfma_f32_16x16x32_f16(a1[m], b1[n], acc[m][n], 0, 0, 0);
    __builtin_amdgcn_s_setprio(0);
    MEMFENCE;
    __builtin_amdgcn_s_barrier();  // buf[cur] fully consumed; t+1 may overwrite next iter
    MEMFENCE;
  }

  // epilogue: C/D layout col = lane&15, row = (lane>>4)*4 + reg
  const int r0 = hi * 4;
  const int c0 = frow;
#pragma unroll
  for (int n = 0; n < NW; n++) {
    const int col = bcol + wc + n * 16 + c0;
    const float bv = bias[col];
#pragma unroll
    for (int m = 0; m < 2; m++) {
#pragma unroll
      for (int r = 0; r < 4; r++) {
        const int row = brow + wr + m * 16 + r0 + r;
        float v = acc[m][n][r] + bv;
        if (EPI == 1) v = 0.5f * tanhf(v);
        if (EPI == 2)
          ((float*)Cout)[(size_t)row * N + col] = v;
        else
          ((_Float16*)Cout)[(size_t)row * N + col] = (_Float16)v;
      }
    }
  }
}

// ---------------------------------------------------------------------------
extern "C" void kernel_launch(void* const* d_in, const int* in_sizes, int n_in,
                              void* d_out, int out_size, void* d_ws,
                              size_t ws_size, hipStream_t stream) {
  (void)in_sizes;
  (void)n_in;
  (void)out_size;
  (void)ws_size;

  const float* x = (const float*)d_in[0];        // [4096,1024]
  const float* W_embed = (const float*)d_in[1];  // [2048,1024]
  const float* b_embed = (const float*)d_in[2];  // [2048]
  const float* W_layers = (const float*)d_in[3]; // [3,2048,2048]
  const float* b_layers = (const float*)d_in[4]; // [3,2048]
  const float* W_head = (const float*)d_in[5];   // [1024,2048]
  const float* b_head = (const float*)d_in[6];   // [1024]

  const int B = 4096, I = 1024, H = 2048, O = 1024;

  char* w = (char*)d_ws;
  auto carve = [&](size_t bytes) {
    char* p = w;
    w += (bytes + 255) & ~(size_t)255;
    return p;
  };
  _Float16* xh = (_Float16*)carve((size_t)B * I * 2);
  _Float16* Weh = (_Float16*)carve((size_t)H * I * 2);
  _Float16* Wlh = (_Float16*)carve((size_t)3 * H * H * 2);
  _Float16* Whh = (_Float16*)carve((size_t)O * H * 2);
  _Float16* bufE = (_Float16*)carve((size_t)B * H * 2);
  _Float16* bufA = (_Float16*)carve((size_t)B * H * 2);

  const long n0 = (long)B * I, n1 = (long)H * I, n2 = (long)3 * H * H,
             n3 = (long)O * H;
  const long nb0 = n0 / 2048, nb1 = n1 / 2048, nb2 = n2 / 2048,
             nb3 = n3 / 2048;
  cvt_all<<<(int)(nb0 + nb1 + nb2 + nb3), 256, 0, stream>>>(
      x, W_embed, W_layers, W_head, xh, Weh, Wlh, Whh, nb0, nb1, nb2);

  dim3 blk(512);
  // all grids: 32x16 tiles = 512 blocks = 2 blocks/CU
  // x_emb = x @ W_embed^T + b_embed            [B,H], f16
  gemmf<0, 4><<<512, blk, 0, stream>>>(xh, Weh, b_embed, bufE, H, I);
  // h0 = 0.5*tanh(x_emb @ W0^T + b0)           [B,H], f16
  gemmf<1, 4><<<512, blk, 0, stream>>>(bufE, Wlh, b_layers, bufA, H, H);
  // h1 = 0.5*tanh(h0 @ W1^T + b1)              [B,H], f16
  gemmf<1, 4><<<512, blk, 0, stream>>>(bufA, Wlh + (size_t)H * H,
                                       b_layers + H, bufE, H, H);
  // h2 = 0.5*tanh(h1 @ W2^T + b2)              [B,H], f16
  gemmf<1, 4><<<512, blk, 0, stream>>>(bufE, Wlh + (size_t)2 * H * H,
                                       b_layers + 2 * H, bufA, H, H);
  // out = h2 @ W_head^T + b_head               [B,O], f32  (BN=64)
  gemmf<2, 2><<<512, blk, 0, stream>>>(bufA, Whh, b_head, d_out, O, H);
}

// Round 6
// 200.171 us; speedup vs baseline: 1.1537x; 1.1300x over previous
//
#include <hip/hip_runtime.h>
#include <cmath>

typedef _Float16 half8 __attribute__((ext_vector_type(8)));
typedef float f32x4 __attribute__((ext_vector_type(4)));

#define GLD_LDS16(gptr, lptr)                                                  \
  __builtin_amdgcn_global_load_lds(                                            \
      (const __attribute__((address_space(1))) void*)(gptr),                   \
      (__attribute__((address_space(3))) void*)(lptr), 16, 0, 0)

#define MEMFENCE asm volatile("" ::: "memory")

// ---------------- merged f32 -> f16 conversion (one dispatch) ---------------
__global__ void cvt_all(const float* __restrict__ s0, const float* __restrict__ s1,
                        const float* __restrict__ s2, const float* __restrict__ s3,
                        _Float16* __restrict__ d0, _Float16* __restrict__ d1,
                        _Float16* __restrict__ d2, _Float16* __restrict__ d3,
                        long nb0, long nb1, long nb2) {
  long b = blockIdx.x;
  const float* s;
  _Float16* d;
  if (b < nb0) {
    s = s0; d = d0;
  } else if (b < nb0 + nb1) {
    s = s1; d = d1; b -= nb0;
  } else if (b < nb0 + nb1 + nb2) {
    s = s2; d = d2; b -= nb0 + nb1;
  } else {
    s = s3; d = d3; b -= nb0 + nb1 + nb2;
  }
  long i = b * 2048 + (long)threadIdx.x * 8;
  const float4* p = (const float4*)(s + i);
  float4 a = p[0];
  float4 c = p[1];
  half8 h = {(_Float16)a.x, (_Float16)a.y, (_Float16)a.z, (_Float16)a.w,
             (_Float16)c.x, (_Float16)c.y, (_Float16)c.z, (_Float16)c.w};
  *(half8*)(d + i) = h;
}

// ---------------- GEMM: C[m,n] = sum_k A[m,k]*B[n,k]  (both K-major) --------
// EPI: 0 = acc+bias -> f16 ; 1 = 0.5*tanh(acc+bias) -> f16 ; 2 = acc+bias -> f32
// NW:  B-fragments per wave. BN = NW*32 (4 -> BN=128, 2 -> BN=64).
// BM=256, BK=64, 512 threads = 8 waves (4M x 2N), wave tile 64 x (BN/2).
// TRIPLE-buffered LDS (144/120 KB, 1 blk/CU): stage distance = 2 K-tiles,
// steady-state wait is vmcnt(3) — never drains in the loop (T4).
// m201 phase anatomy (2 phases/K-tile):
//   { 8 ds_reads (pre-barrier)  || stage chunk of tile t+2
//     -> s_barrier -> (compiler lgkmcnt) -> setprio(1) 16 MFMA setprio(0)
//     -> s_barrier }
// Reads of tile t were validated by the vmcnt+barrier 2 phases earlier;
// buffer-reuse WAR is safe because each wave's reads retire (lgkmcnt before
// its MFMA) before it passes the phase-end barrier.
// T2 XOR swizzle (chunk^row&7) via pre-swizzled global source + ds_read.
// Grid: 256 blocks = 16x16 tiles; 2-D XCD rects (4 rows x 8 cols of tiles).
template <int EPI, int NW>
__global__ __launch_bounds__(512, 2) void gemm3b(
    const _Float16* __restrict__ A, const _Float16* __restrict__ Bm,
    const float* __restrict__ bias, void* __restrict__ Cout, int N, int K) {
  constexpr int BN = NW * 32;
  constexpr int BLOADS = BN / 64;  // B staging issues per tile (2 or 1)
  __shared__ _Float16 As[3][256 * 64];
  __shared__ _Float16 Bs[3][BN * 64];

  const int tid = threadIdx.x;
  const int lane = tid & 63;
  const int wave = tid >> 6;

  // 2-D XCD rects on the 16x16 tile grid (256 blocks): each XCD owns 4x8.
  const int bid = blockIdx.x;
  const int xcd = bid & 7;
  const int idx = bid >> 3;  // 0..31
  const int brow = ((xcd >> 1) * 4 + (idx & 3)) * 256;
  const int bcol = ((xcd & 1) * 8 + (idx >> 2)) * BN;

  const int wr = (wave >> 1) * 64;        // 4 M-waves, 64 rows each
  const int wc = (wave & 1) * (BN / 2);   // 2 N-waves

  // staging: 512 thr x 16B covers 64 rows x 64 f16 cols per issue.
  const int sr = tid >> 3;
  const int sc = ((tid & 7) ^ (sr & 7)) * 8;  // T2: pre-swizzled source col
  const _Float16* Ag = A + (size_t)(brow + sr) * K + sc;
  const _Float16* Bg = Bm + (size_t)(bcol + sr) * K + sc;
  const int ldst = tid * 8;  // linear LDS dest (required by global_load_lds)

  // MFMA fragment geometry (16x16x32): row=lane&15, k-half=(lane>>4)*8
  const int frow = lane & 15;
  const int hi = lane >> 4;
  const int xr = lane & 7;  // read-side XOR (matches source swizzle)

  int aoff[4], boff[NW];
#pragma unroll
  for (int m = 0; m < 4; m++) aoff[m] = (wr + m * 16 + frow) * 64;
#pragma unroll
  for (int n = 0; n < NW; n++) boff[n] = (wc + n * 16 + frow) * 64;
  const int ch0 = (hi ^ xr) * 8;
  const int ch1 = ((4 + hi) ^ xr) * 8;

  f32x4 acc[4][NW];
#pragma unroll
  for (int m = 0; m < 4; m++)
#pragma unroll
    for (int n = 0; n < NW; n++) acc[m][n] = f32x4{0.f, 0.f, 0.f, 0.f};

  // rotating buffer pointers: read sa0/sb0; stage target sa2/sb2 (tile t+2)
  _Float16* sa0 = As[0]; _Float16* sa1 = As[1]; _Float16* sa2 = As[2];
  _Float16* sb0 = Bs[0]; _Float16* sb1 = Bs[1]; _Float16* sb2 = Bs[2];

  // stage chunk 1: A rows 0..127 (2 issues) + B issue 0            (3 loads)
  auto stage1 = [&](_Float16* sa, _Float16* sb, int t) {
    const _Float16* ag = Ag + t * 64;
    GLD_LDS16(ag, sa + ldst);
    GLD_LDS16(ag + (size_t)64 * K, sa + 4096 + ldst);
    GLD_LDS16(Bg + t * 64, sb + ldst);
  };
  // stage chunk 2: A rows 128..255 (2 issues) + B issue 1 if any (2-3 loads)
  auto stage2 = [&](_Float16* sa, _Float16* sb, int t) {
    const _Float16* ag = Ag + t * 64;
    GLD_LDS16(ag + (size_t)128 * K, sa + 8192 + ldst);
    GLD_LDS16(ag + (size_t)192 * K, sa + 12288 + ldst);
    if constexpr (BLOADS == 2)
      GLD_LDS16(Bg + t * 64 + (size_t)64 * K, sb + 4096 + ldst);
  };

  const int nt = K >> 6;  // >= 16 always here

  // prologue: stage tiles 0 and 1; wait tile 0 only (tile 1 stays in flight)
  stage1(sa0, sb0, 0); stage2(sa0, sb0, 0);
  stage1(sa1, sb1, 1); stage2(sa1, sb1, 1);
  if constexpr (NW == 4)
    asm volatile("s_waitcnt vmcnt(6)" ::: "memory");
  else
    asm volatile("s_waitcnt vmcnt(5)" ::: "memory");
  __builtin_amdgcn_s_barrier();
  MEMFENCE;

  for (int t = 0; t < nt; ++t) {
    // ============ phase 1 (kk = 0) ============
    half8 a0[4], b0[NW];
#pragma unroll
    for (int m = 0; m < 4; m++) a0[m] = *(const half8*)(sa0 + aoff[m] + ch0);
#pragma unroll
    for (int n = 0; n < NW; n++) b0[n] = *(const half8*)(sb0 + boff[n] + ch0);
    if (t + 2 < nt) stage1(sa2, sb2, t + 2);
    MEMFENCE;  // pin reads + stage issues before the barrier
    __builtin_amdgcn_s_barrier();
    __builtin_amdgcn_s_setprio(1);
#pragma unroll
    for (int m = 0; m < 4; m++)
#pragma unroll
      for (int n = 0; n < NW; n++)
        acc[m][n] =
            __builtin_amdgcn_mfma_f32_16x16x32_f16(a0[m], b0[n], acc[m][n], 0, 0, 0);
    __builtin_amdgcn_s_setprio(0);
    MEMFENCE;
    __builtin_amdgcn_s_barrier();
    MEMFENCE;

    // ============ phase 2 (kk = 1) ============
    half8 a1[4], b1[NW];
#pragma unroll
    for (int m = 0; m < 4; m++) a1[m] = *(const half8*)(sa0 + aoff[m] + ch1);
#pragma unroll
    for (int n = 0; n < NW; n++) b1[n] = *(const half8*)(sb0 + boff[n] + ch1);
    if (t + 2 < nt) {
      // outstanding: S2(t+1) [2-3] + S1(t+2) [3]; wait until 3 remain
      // -> tile t+1 fully in LDS, tile t+2's chunk 1 still in flight.
      asm volatile("s_waitcnt vmcnt(3)" ::: "memory");
      stage2(sa2, sb2, t + 2);
    } else if (t + 1 < nt) {
      asm volatile("s_waitcnt vmcnt(0)" ::: "memory");  // fires once, near end
    }
    MEMFENCE;
    __builtin_amdgcn_s_barrier();
    __builtin_amdgcn_s_setprio(1);
#pragma unroll
    for (int m = 0; m < 4; m++)
#pragma unroll
      for (int n = 0; n < NW; n++)
        acc[m][n] =
            __builtin_amdgcn_mfma_f32_16x16x32_f16(a1[m], b1[n], acc[m][n], 0, 0, 0);
    __builtin_amdgcn_s_setprio(0);
    MEMFENCE;
    __builtin_amdgcn_s_barrier();
    MEMFENCE;

    // rotate buffers (t -> t+1)
    _Float16* ta = sa0; sa0 = sa1; sa1 = sa2; sa2 = ta;
    _Float16* tb = sb0; sb0 = sb1; sb1 = sb2; sb2 = tb;
  }

  // epilogue: C/D layout col = lane&15, row = (lane>>4)*4 + reg
  const int r0 = hi * 4;
  const int c0 = frow;
#pragma unroll
  for (int n = 0; n < NW; n++) {
    const int col = bcol + wc + n * 16 + c0;
    const float bv = bias[col];
#pragma unroll
    for (int m = 0; m < 4; m++) {
#pragma unroll
      for (int r = 0; r < 4; r++) {
        const int row = brow + wr + m * 16 + r0 + r;
        float v = acc[m][n][r] + bv;
        if (EPI == 1) v = 0.5f * tanhf(v);
        if (EPI == 2)
          ((float*)Cout)[(size_t)row * N + col] = v;
        else
          ((_Float16*)Cout)[(size_t)row * N + col] = (_Float16)v;
      }
    }
  }
}

// ---------------------------------------------------------------------------
extern "C" void kernel_launch(void* const* d_in, const int* in_sizes, int n_in,
                              void* d_out, int out_size, void* d_ws,
                              size_t ws_size, hipStream_t stream) {
  (void)in_sizes;
  (void)n_in;
  (void)out_size;
  (void)ws_size;

  const float* x = (const float*)d_in[0];        // [4096,1024]
  const float* W_embed = (const float*)d_in[1];  // [2048,1024]
  const float* b_embed = (const float*)d_in[2];  // [2048]
  const float* W_layers = (const float*)d_in[3]; // [3,2048,2048]
  const float* b_layers = (const float*)d_in[4]; // [3,2048]
  const float* W_head = (const float*)d_in[5];   // [1024,2048]
  const float* b_head = (const float*)d_in[6];   // [1024]

  const int B = 4096, I = 1024, H = 2048, O = 1024;

  char* w = (char*)d_ws;
  auto carve = [&](size_t bytes) {
    char* p = w;
    w += (bytes + 255) & ~(size_t)255;
    return p;
  };
  _Float16* xh = (_Float16*)carve((size_t)B * I * 2);
  _Float16* Weh = (_Float16*)carve((size_t)H * I * 2);
  _Float16* Wlh = (_Float16*)carve((size_t)3 * H * H * 2);
  _Float16* Whh = (_Float16*)carve((size_t)O * H * 2);
  _Float16* bufE = (_Float16*)carve((size_t)B * H * 2);
  _Float16* bufA = (_Float16*)carve((size_t)B * H * 2);

  const long n0 = (long)B * I, n1 = (long)H * I, n2 = (long)3 * H * H,
             n3 = (long)O * H;
  const long nb0 = n0 / 2048, nb1 = n1 / 2048, nb2 = n2 / 2048,
             nb3 = n3 / 2048;
  cvt_all<<<(int)(nb0 + nb1 + nb2 + nb3), 256, 0, stream>>>(
      x, W_embed, W_layers, W_head, xh, Weh, Wlh, Whh, nb0, nb1, nb2);

  dim3 blk(512);
  // all grids: 16x16 tiles = 256 blocks = 1 block/CU
  // x_emb = x @ W_embed^T + b_embed            [B,H], f16
  gemm3b<0, 4><<<256, blk, 0, stream>>>(xh, Weh, b_embed, bufE, H, I);
  // h0 = 0.5*tanh(x_emb @ W0^T + b0)           [B,H], f16
  gemm3b<1, 4><<<256, blk, 0, stream>>>(bufE, Wlh, b_layers, bufA, H, H);
  // h1 = 0.5*tanh(h0 @ W1^T + b1)              [B,H], f16
  gemm3b<1, 4><<<256, blk, 0, stream>>>(bufA, Wlh + (size_t)H * H,
                                        b_layers + H, bufE, H, H);
  // h2 = 0.5*tanh(h1 @ W2^T + b2)              [B,H], f16
  gemm3b<1, 4><<<256, blk, 0, stream>>>(bufE, Wlh + (size_t)2 * H * H,
                                        b_layers + 2 * H, bufA, H, H);
  // out = h2 @ W_head^T + b_head               [B,O], f32  (BN=64)
  gemm3b<2, 2><<<256, blk, 0, stream>>>(bufA, Whh, b_head, d_out, O, H);
}

// Round 7
// 191.858 us; speedup vs baseline: 1.2037x; 1.0433x over previous
//
#include <hip/hip_runtime.h>
#include <cmath>

typedef _Float16 half8 __attribute__((ext_vector_type(8)));
typedef float f32x4 __attribute__((ext_vector_type(4)));

#define GLD_LDS16(gptr, lptr)                                                  \
  __builtin_amdgcn_global_load_lds(                                            \
      (const __attribute__((address_space(1))) void*)(gptr),                   \
      (__attribute__((address_space(3))) void*)(lptr), 16, 0, 0)

#define MEMFENCE asm volatile("" ::: "memory")

// ---------------- merged f32 -> f16 conversion (one dispatch) ---------------
__global__ void cvt_all(const float* __restrict__ s0, const float* __restrict__ s1,
                        const float* __restrict__ s2, const float* __restrict__ s3,
                        _Float16* __restrict__ d0, _Float16* __restrict__ d1,
                        _Float16* __restrict__ d2, _Float16* __restrict__ d3,
                        long nb0, long nb1, long nb2) {
  long b = blockIdx.x;
  const float* s;
  _Float16* d;
  if (b < nb0) {
    s = s0; d = d0;
  } else if (b < nb0 + nb1) {
    s = s1; d = d1; b -= nb0;
  } else if (b < nb0 + nb1 + nb2) {
    s = s2; d = d2; b -= nb0 + nb1;
  } else {
    s = s3; d = d3; b -= nb0 + nb1 + nb2;
  }
  long i = b * 2048 + (long)threadIdx.x * 8;
  const float4* p = (const float4*)(s + i);
  float4 a = p[0];
  float4 c = p[1];
  half8 h = {(_Float16)a.x, (_Float16)a.y, (_Float16)a.z, (_Float16)a.w,
             (_Float16)c.x, (_Float16)c.y, (_Float16)c.z, (_Float16)c.w};
  *(half8*)(d + i) = h;
}

// ---------------- GEMM: C[m,n] = sum_k A[m,k]*B[n,k]  (both K-major) --------
// EPI: 0 = acc+bias -> f16 ; 1 = 0.5*tanh(acc+bias) -> f16 ; 2 = acc+bias -> f32
// NW:  B-fragments per wave. BN = NW*32 (4 -> BN=128, 2 -> BN=64).
// BM=256, BK=64, 512 threads = 8 waves (4M x 2N), wave tile 64 x (BN/2).
// ONE barrier per K-tile, ~32 MFMA per barrier (AITER anatomy), triple-buffer
// LDS (distance-2 prefetch), counted vmcnt(LPT) — never drains mid-loop.
// Per iteration t:
//   16 ds_reads (tile t, both kk)  || stage tile t+2 (LPT gld_lds)
//   s_waitcnt vmcnt(LPT)   -> tile t+1 landed (t+2 stays in flight)
//   s_waitcnt lgkmcnt(0)   -> my LDS reads drained (WAR-safe vs re-stage)
//   s_barrier              -> publishes t+1; licenses staging into old buf
//   setprio(1) 32 MFMA setprio(0)
// RAW: tile t validated at iter t-1 (vmcnt+barrier). WAR: all waves drained
// reads of buf before the barrier; MFMA uses registers only.
// T2 XOR swizzle (chunk^row&7) via pre-swizzled global source + ds_read.
// Grid: 256 blocks = 16x16 tiles; 2-D XCD rects (4 rows x 8 cols of tiles).
template <int EPI, int NW>
__global__ __launch_bounds__(512, 2) void gemm1b(
    const _Float16* __restrict__ A, const _Float16* __restrict__ Bm,
    const float* __restrict__ bias, void* __restrict__ Cout, int N, int K) {
  constexpr int BN = NW * 32;
  constexpr int BLOADS = BN / 64;  // B staging issues per tile (2 or 1)
  __shared__ _Float16 As[3][256 * 64];
  __shared__ _Float16 Bs[3][BN * 64];

  const int tid = threadIdx.x;
  const int lane = tid & 63;
  const int wave = tid >> 6;

  // 2-D XCD rects on the 16x16 tile grid (256 blocks): each XCD owns 4x8.
  const int bid = blockIdx.x;
  const int xcd = bid & 7;
  const int idx = bid >> 3;  // 0..31
  const int brow = ((xcd >> 1) * 4 + (idx & 3)) * 256;
  const int bcol = ((xcd & 1) * 8 + (idx >> 2)) * BN;

  const int wr = (wave >> 1) * 64;        // 4 M-waves, 64 rows each
  const int wc = (wave & 1) * (BN / 2);   // 2 N-waves

  // staging: 512 thr x 16B covers 64 rows x 64 f16 cols per issue.
  const int sr = tid >> 3;
  const int sc = ((tid & 7) ^ (sr & 7)) * 8;  // T2: pre-swizzled source col
  const _Float16* Ag = A + (size_t)(brow + sr) * K + sc;
  const _Float16* Bg = Bm + (size_t)(bcol + sr) * K + sc;
  const int ldst = tid * 8;  // linear LDS dest (required by global_load_lds)

  // MFMA fragment geometry (16x16x32): row=lane&15, k-half=(lane>>4)*8
  const int frow = lane & 15;
  const int hi = lane >> 4;
  const int xr = lane & 7;  // read-side XOR (matches source swizzle)

  int aoff[4], boff[NW];
#pragma unroll
  for (int m = 0; m < 4; m++) aoff[m] = (wr + m * 16 + frow) * 64;
#pragma unroll
  for (int n = 0; n < NW; n++) boff[n] = (wc + n * 16 + frow) * 64;
  const int ch0 = (hi ^ xr) * 8;
  const int ch1 = ((4 + hi) ^ xr) * 8;

  f32x4 acc[4][NW];
#pragma unroll
  for (int m = 0; m < 4; m++)
#pragma unroll
    for (int n = 0; n < NW; n++) acc[m][n] = f32x4{0.f, 0.f, 0.f, 0.f};

  _Float16* sa0 = As[0]; _Float16* sa1 = As[1]; _Float16* sa2 = As[2];
  _Float16* sb0 = Bs[0]; _Float16* sb1 = Bs[1]; _Float16* sb2 = Bs[2];

  auto stage = [&](_Float16* sa, _Float16* sb, int t) {
    const _Float16* ag = Ag + t * 64;
#pragma unroll
    for (int i = 0; i < 4; i++)
      GLD_LDS16(ag + (size_t)i * 64 * K, sa + i * 4096 + ldst);
#pragma unroll
    for (int i = 0; i < BLOADS; i++)
      GLD_LDS16(Bg + t * 64 + (size_t)i * 64 * K, sb + i * 4096 + ldst);
  };

  const int nt = K >> 6;  // 16 or 32 here

  // prologue: stage tiles 0,1; wait tile 0 (tile 1 stays in flight); publish
  stage(sa0, sb0, 0);
  stage(sa1, sb1, 1);
  if constexpr (NW == 4)
    asm volatile("s_waitcnt vmcnt(6)" ::: "memory");
  else
    asm volatile("s_waitcnt vmcnt(5)" ::: "memory");
  __builtin_amdgcn_s_barrier();
  MEMFENCE;

  for (int t = 0; t < nt; ++t) {
    // ---- LDS reads for tile t (both kk halves) ----
    half8 a0[4], a1[4], b0[NW], b1[NW];
#pragma unroll
    for (int m = 0; m < 4; m++) a0[m] = *(const half8*)(sa0 + aoff[m] + ch0);
#pragma unroll
    for (int n = 0; n < NW; n++) b0[n] = *(const half8*)(sb0 + boff[n] + ch0);
#pragma unroll
    for (int m = 0; m < 4; m++) a1[m] = *(const half8*)(sa0 + aoff[m] + ch1);
#pragma unroll
    for (int n = 0; n < NW; n++) b1[n] = *(const half8*)(sb0 + boff[n] + ch1);

    // ---- prefetch tile t+2 into the buffer freed at iter t-1 ----
    if (t + 2 < nt) {
      stage(sa2, sb2, t + 2);
      if constexpr (NW == 4)
        asm volatile("s_waitcnt vmcnt(6)" ::: "memory");  // t+1 landed
      else
        asm volatile("s_waitcnt vmcnt(5)" ::: "memory");
    } else {
      asm volatile("s_waitcnt vmcnt(0)" ::: "memory");  // tail (loads 1 iter old)
    }
    asm volatile("s_waitcnt lgkmcnt(0)" ::: "memory");  // my reads drained
    __builtin_amdgcn_s_barrier();  // t+1 published; buf recycle licensed
    MEMFENCE;

    // ---- 32 MFMA (NW=4) on registers only ----
    __builtin_amdgcn_s_setprio(1);
#pragma unroll
    for (int m = 0; m < 4; m++)
#pragma unroll
      for (int n = 0; n < NW; n++)
        acc[m][n] =
            __builtin_amdgcn_mfma_f32_16x16x32_f16(a0[m], b0[n], acc[m][n], 0, 0, 0);
#pragma unroll
    for (int m = 0; m < 4; m++)
#pragma unroll
      for (int n = 0; n < NW; n++)
        acc[m][n] =
            __builtin_amdgcn_mfma_f32_16x16x32_f16(a1[m], b1[n], acc[m][n], 0, 0, 0);
    __builtin_amdgcn_s_setprio(0);
    MEMFENCE;

    // rotate buffers (t -> t+1)
    _Float16* ta = sa0; sa0 = sa1; sa1 = sa2; sa2 = ta;
    _Float16* tb = sb0; sb0 = sb1; sb1 = sb2; sb2 = tb;
  }

  // epilogue: C/D layout col = lane&15, row = (lane>>4)*4 + reg
  const int r0 = hi * 4;
  const int c0 = frow;
#pragma unroll
  for (int n = 0; n < NW; n++) {
    const int col = bcol + wc + n * 16 + c0;
    const float bv = bias[col];
#pragma unroll
    for (int m = 0; m < 4; m++) {
#pragma unroll
      for (int r = 0; r < 4; r++) {
        const int row = brow + wr + m * 16 + r0 + r;
        float v = acc[m][n][r] + bv;
        if (EPI == 1) v = 0.5f * tanhf(v);
        if (EPI == 2)
          ((float*)Cout)[(size_t)row * N + col] = v;
        else
          ((_Float16*)Cout)[(size_t)row * N + col] = (_Float16)v;
      }
    }
  }
}

// ---------------------------------------------------------------------------
extern "C" void kernel_launch(void* const* d_in, const int* in_sizes, int n_in,
                              void* d_out, int out_size, void* d_ws,
                              size_t ws_size, hipStream_t stream) {
  (void)in_sizes;
  (void)n_in;
  (void)out_size;
  (void)ws_size;

  const float* x = (const float*)d_in[0];        // [4096,1024]
  const float* W_embed = (const float*)d_in[1];  // [2048,1024]
  const float* b_embed = (const float*)d_in[2];  // [2048]
  const float* W_layers = (const float*)d_in[3]; // [3,2048,2048]
  const float* b_layers = (const float*)d_in[4]; // [3,2048]
  const float* W_head = (const float*)d_in[5];   // [1024,2048]
  const float* b_head = (const float*)d_in[6];   // [1024]

  const int B = 4096, I = 1024, H = 2048, O = 1024;

  char* w = (char*)d_ws;
  auto carve = [&](size_t bytes) {
    char* p = w;
    w += (bytes + 255) & ~(size_t)255;
    return p;
  };
  _Float16* xh = (_Float16*)carve((size_t)B * I * 2);
  _Float16* Weh = (_Float16*)carve((size_t)H * I * 2);
  _Float16* Wlh = (_Float16*)carve((size_t)3 * H * H * 2);
  _Float16* Whh = (_Float16*)carve((size_t)O * H * 2);
  _Float16* bufE = (_Float16*)carve((size_t)B * H * 2);
  _Float16* bufA = (_Float16*)carve((size_t)B * H * 2);

  const long n0 = (long)B * I, n1 = (long)H * I, n2 = (long)3 * H * H,
             n3 = (long)O * H;
  const long nb0 = n0 / 2048, nb1 = n1 / 2048, nb2 = n2 / 2048,
             nb3 = n3 / 2048;
  cvt_all<<<(int)(nb0 + nb1 + nb2 + nb3), 256, 0, stream>>>(
      x, W_embed, W_layers, W_head, xh, Weh, Wlh, Whh, nb0, nb1, nb2);

  dim3 blk(512);
  // all grids: 16x16 tiles = 256 blocks = 1 block/CU
  // x_emb = x @ W_embed^T + b_embed            [B,H], f16
  gemm1b<0, 4><<<256, blk, 0, stream>>>(xh, Weh, b_embed, bufE, H, I);
  // h0 = 0.5*tanh(x_emb @ W0^T + b0)           [B,H], f16
  gemm1b<1, 4><<<256, blk, 0, stream>>>(bufE, Wlh, b_layers, bufA, H, H);
  // h1 = 0.5*tanh(h0 @ W1^T + b1)              [B,H], f16
  gemm1b<1, 4><<<256, blk, 0, stream>>>(bufA, Wlh + (size_t)H * H,
                                        b_layers + H, bufE, H, H);
  // h2 = 0.5*tanh(h1 @ W2^T + b2)              [B,H], f16
  gemm1b<1, 4><<<256, blk, 0, stream>>>(bufE, Wlh + (size_t)2 * H * H,
                                        b_layers + 2 * H, bufA, H, H);
  // out = h2 @ W_head^T + b_head               [B,O], f32  (BN=64)
  gemm1b<2, 2><<<256, blk, 0, stream>>>(bufA, Whh, b_head, d_out, O, H);
}

// Round 8
// 190.870 us; speedup vs baseline: 1.2099x; 1.0052x over previous
//
#include <hip/hip_runtime.h>
#include <cmath>

typedef _Float16 half8 __attribute__((ext_vector_type(8)));
typedef float f32x4 __attribute__((ext_vector_type(4)));

#define GLD_LDS16(gptr, lptr)                                                  \
  __builtin_amdgcn_global_load_lds(                                            \
      (const __attribute__((address_space(1))) void*)(gptr),                   \
      (__attribute__((address_space(3))) void*)(lptr), 16, 0, 0)

#define MEMFENCE asm volatile("" ::: "memory")

// ---------------- merged f32 -> f16 conversion (one dispatch) ---------------
__global__ void cvt_all(const float* __restrict__ s0, const float* __restrict__ s1,
                        const float* __restrict__ s2, const float* __restrict__ s3,
                        _Float16* __restrict__ d0, _Float16* __restrict__ d1,
                        _Float16* __restrict__ d2, _Float16* __restrict__ d3,
                        long nb0, long nb1, long nb2) {
  long b = blockIdx.x;
  const float* s;
  _Float16* d;
  if (b < nb0) {
    s = s0; d = d0;
  } else if (b < nb0 + nb1) {
    s = s1; d = d1; b -= nb0;
  } else if (b < nb0 + nb1 + nb2) {
    s = s2; d = d2; b -= nb0 + nb1;
  } else {
    s = s3; d = d3; b -= nb0 + nb1 + nb2;
  }
  long i = b * 2048 + (long)threadIdx.x * 8;
  const float4* p = (const float4*)(s + i);
  float4 a = p[0];
  float4 c = p[1];
  half8 h = {(_Float16)a.x, (_Float16)a.y, (_Float16)a.z, (_Float16)a.w,
             (_Float16)c.x, (_Float16)c.y, (_Float16)c.z, (_Float16)c.w};
  *(half8*)(d + i) = h;
}

// ---------------- GEMM: C[m,n] = sum_k A[m,k]*B[n,k]  (both K-major) --------
// EPI: 0 = acc+bias -> f16 ; 1 = 0.5*tanh(acc+bias) -> f16 ; 2 = acc+bias -> f32
// NW:  B-fragments per wave. BN = NW*32 (4 -> BN=128, 2 -> BN=64).
// BM=256, BK=64, 512 threads = 8 waves (4M x 2N), wave tile 64 x (BN/2).
// Triple-buffered LDS, distance-2 prefetch, ONE barrier per K-tile, counted
// vmcnt — never drains mid-loop. kk-halves SOFTWARE-PIPELINED so ds_reads
// always execute under MFMA issue (LDS pipe and matrix pipe overlap):
//   iter t:  stage(t+2) ; issue reads kk1(t) ; MFMA kk0(t)   <- overlap
//            vmcnt(6) [t+1 landed] ; lgkmcnt(0) [my reads drained: WAR]
//            s_barrier [publish t+1, license recycle of buf(t)]
//            rotate ; issue reads kk0(t+1) ; MFMA kk1(t)     <- overlap
// RAW: reads of tile t follow t's validating vmcnt+barrier (prev iter).
// WAR: every wave drains its reads (lgkmcnt 0) before the barrier that
// licenses re-staging into the buffer it was reading.
// T2 XOR swizzle (chunk^row&7) via pre-swizzled global source + ds_read.
// Grid: 256 blocks = 16x16 tiles; 2-D XCD rects (4 rows x 8 cols of tiles).
template <int EPI, int NW>
__global__ __launch_bounds__(512, 2) void gemmsp(
    const _Float16* __restrict__ A, const _Float16* __restrict__ Bm,
    const float* __restrict__ bias, void* __restrict__ Cout, int N, int K) {
  constexpr int BN = NW * 32;
  constexpr int BLOADS = BN / 64;  // B staging issues per tile (2 or 1)
  constexpr int LPT = 4 + BLOADS;  // gld_lds issues per tile
  __shared__ _Float16 As[3][256 * 64];
  __shared__ _Float16 Bs[3][BN * 64];

  const int tid = threadIdx.x;
  const int lane = tid & 63;
  const int wave = tid >> 6;

  // 2-D XCD rects on the 16x16 tile grid (256 blocks): each XCD owns 4x8.
  const int bid = blockIdx.x;
  const int xcd = bid & 7;
  const int idx = bid >> 3;  // 0..31
  const int brow = ((xcd >> 1) * 4 + (idx & 3)) * 256;
  const int bcol = ((xcd & 1) * 8 + (idx >> 2)) * BN;

  const int wr = (wave >> 1) * 64;        // 4 M-waves, 64 rows each
  const int wc = (wave & 1) * (BN / 2);   // 2 N-waves

  // staging: 512 thr x 16B covers 64 rows x 64 f16 cols per issue.
  const int sr = tid >> 3;
  const int sc = ((tid & 7) ^ (sr & 7)) * 8;  // T2: pre-swizzled source col
  const _Float16* Ag = A + (size_t)(brow + sr) * K + sc;
  const _Float16* Bg = Bm + (size_t)(bcol + sr) * K + sc;
  const int ldst = tid * 8;  // linear LDS dest (required by global_load_lds)

  // MFMA fragment geometry (16x16x32): row=lane&15, k-half=(lane>>4)*8
  const int frow = lane & 15;
  const int hi = lane >> 4;
  const int xr = lane & 7;  // read-side XOR (matches source swizzle)

  int aoff[4], boff[NW];
#pragma unroll
  for (int m = 0; m < 4; m++) aoff[m] = (wr + m * 16 + frow) * 64;
#pragma unroll
  for (int n = 0; n < NW; n++) boff[n] = (wc + n * 16 + frow) * 64;
  const int ch0 = (hi ^ xr) * 8;
  const int ch1 = ((4 + hi) ^ xr) * 8;

  f32x4 acc[4][NW];
#pragma unroll
  for (int m = 0; m < 4; m++)
#pragma unroll
    for (int n = 0; n < NW; n++) acc[m][n] = f32x4{0.f, 0.f, 0.f, 0.f};

  _Float16* sa0 = As[0]; _Float16* sa1 = As[1]; _Float16* sa2 = As[2];
  _Float16* sb0 = Bs[0]; _Float16* sb1 = Bs[1]; _Float16* sb2 = Bs[2];

  auto stage = [&](_Float16* sa, _Float16* sb, int t) {
    const _Float16* ag = Ag + t * 64;
#pragma unroll
    for (int i = 0; i < 4; i++)
      GLD_LDS16(ag + (size_t)i * 64 * K, sa + i * 4096 + ldst);
#pragma unroll
    for (int i = 0; i < BLOADS; i++)
      GLD_LDS16(Bg + t * 64 + (size_t)i * 64 * K, sb + i * 4096 + ldst);
  };

  const int nt = K >> 6;

  // prologue: stage tiles 0,1; wait tile 0 (tile 1 in flight); publish
  stage(sa0, sb0, 0);
  stage(sa1, sb1, 1);
  asm volatile("s_waitcnt vmcnt(%0)" ::"i"(LPT) : "memory");
  __builtin_amdgcn_s_barrier();
  MEMFENCE;

  // pre-read kk0 of tile 0
  half8 a0[4], b0[NW];
#pragma unroll
  for (int m = 0; m < 4; m++) a0[m] = *(const half8*)(sa0 + aoff[m] + ch0);
#pragma unroll
  for (int n = 0; n < NW; n++) b0[n] = *(const half8*)(sb0 + boff[n] + ch0);

  for (int t = 0; t < nt; ++t) {
    const bool pf2 = (t + 2 < nt);

    // ---- prefetch tile t+2 into the buffer recycled at iter t-1 ----
    if (pf2) stage(sa2, sb2, t + 2);

    // ---- issue reads kk1(t); MFMA kk0(t) overlaps their execution ----
    half8 a1[4], b1[NW];
#pragma unroll
    for (int m = 0; m < 4; m++) a1[m] = *(const half8*)(sa0 + aoff[m] + ch1);
#pragma unroll
    for (int n = 0; n < NW; n++) b1[n] = *(const half8*)(sb0 + boff[n] + ch1);
    __builtin_amdgcn_s_setprio(1);
#pragma unroll
    for (int m = 0; m < 4; m++)
#pragma unroll
      for (int n = 0; n < NW; n++)
        acc[m][n] =
            __builtin_amdgcn_mfma_f32_16x16x32_f16(a0[m], b0[n], acc[m][n], 0, 0, 0);
    __builtin_amdgcn_s_setprio(0);

    // ---- tile boundary: t+1 landed, my reads drained, publish/license ----
    if (pf2)
      asm volatile("s_waitcnt vmcnt(%0)" ::"i"(LPT) : "memory");
    else
      asm volatile("s_waitcnt vmcnt(0)" ::: "memory");
    asm volatile("s_waitcnt lgkmcnt(0)" ::: "memory");
    __builtin_amdgcn_s_barrier();
    MEMFENCE;

    // rotate buffers (t -> t+1)
    _Float16* ta = sa0; sa0 = sa1; sa1 = sa2; sa2 = ta;
    _Float16* tb = sb0; sb0 = sb1; sb1 = sb2; sb2 = tb;

    // ---- issue reads kk0(t+1); MFMA kk1(t) overlaps their execution ----
    if (t + 1 < nt) {
#pragma unroll
      for (int m = 0; m < 4; m++) a0[m] = *(const half8*)(sa0 + aoff[m] + ch0);
#pragma unroll
      for (int n = 0; n < NW; n++) b0[n] = *(const half8*)(sb0 + boff[n] + ch0);
    }
    __builtin_amdgcn_s_setprio(1);
#pragma unroll
    for (int m = 0; m < 4; m++)
#pragma unroll
      for (int n = 0; n < NW; n++)
        acc[m][n] =
            __builtin_amdgcn_mfma_f32_16x16x32_f16(a1[m], b1[n], acc[m][n], 0, 0, 0);
    __builtin_amdgcn_s_setprio(0);
  }

  // epilogue: C/D layout col = lane&15, row = (lane>>4)*4 + reg
  const int r0 = hi * 4;
  const int c0 = frow;
#pragma unroll
  for (int n = 0; n < NW; n++) {
    const int col = bcol + wc + n * 16 + c0;
    const float bv = bias[col];
#pragma unroll
    for (int m = 0; m < 4; m++) {
#pragma unroll
      for (int r = 0; r < 4; r++) {
        const int row = brow + wr + m * 16 + r0 + r;
        float v = acc[m][n][r] + bv;
        if (EPI == 1) v = 0.5f * tanhf(v);
        if (EPI == 2)
          ((float*)Cout)[(size_t)row * N + col] = v;
        else
          ((_Float16*)Cout)[(size_t)row * N + col] = (_Float16)v;
      }
    }
  }
}

// ---------------------------------------------------------------------------
extern "C" void kernel_launch(void* const* d_in, const int* in_sizes, int n_in,
                              void* d_out, int out_size, void* d_ws,
                              size_t ws_size, hipStream_t stream) {
  (void)in_sizes;
  (void)n_in;
  (void)out_size;
  (void)ws_size;

  const float* x = (const float*)d_in[0];        // [4096,1024]
  const float* W_embed = (const float*)d_in[1];  // [2048,1024]
  const float* b_embed = (const float*)d_in[2];  // [2048]
  const float* W_layers = (const float*)d_in[3]; // [3,2048,2048]
  const float* b_layers = (const float*)d_in[4]; // [3,2048]
  const float* W_head = (const float*)d_in[5];   // [1024,2048]
  const float* b_head = (const float*)d_in[6];   // [1024]

  const int B = 4096, I = 1024, H = 2048, O = 1024;

  char* w = (char*)d_ws;
  auto carve = [&](size_t bytes) {
    char* p = w;
    w += (bytes + 255) & ~(size_t)255;
    return p;
  };
  _Float16* xh = (_Float16*)carve((size_t)B * I * 2);
  _Float16* Weh = (_Float16*)carve((size_t)H * I * 2);
  _Float16* Wlh = (_Float16*)carve((size_t)3 * H * H * 2);
  _Float16* Whh = (_Float16*)carve((size_t)O * H * 2);
  _Float16* bufE = (_Float16*)carve((size_t)B * H * 2);
  _Float16* bufA = (_Float16*)carve((size_t)B * H * 2);

  const long n0 = (long)B * I, n1 = (long)H * I, n2 = (long)3 * H * H,
             n3 = (long)O * H;
  const long nb0 = n0 / 2048, nb1 = n1 / 2048, nb2 = n2 / 2048,
             nb3 = n3 / 2048;
  cvt_all<<<(int)(nb0 + nb1 + nb2 + nb3), 256, 0, stream>>>(
      x, W_embed, W_layers, W_head, xh, Weh, Wlh, Whh, nb0, nb1, nb2);

  dim3 blk(512);
  // all grids: 16x16 tiles = 256 blocks = 1 block/CU
  // x_emb = x @ W_embed^T + b_embed            [B,H], f16
  gemmsp<0, 4><<<256, blk, 0, stream>>>(xh, Weh, b_embed, bufE, H, I);
  // h0 = 0.5*tanh(x_emb @ W0^T + b0)           [B,H], f16
  gemmsp<1, 4><<<256, blk, 0, stream>>>(bufE, Wlh, b_layers, bufA, H, H);
  // h1 = 0.5*tanh(h0 @ W1^T + b1)              [B,H], f16
  gemmsp<1, 4><<<256, blk, 0, stream>>>(bufA, Wlh + (size_t)H * H,
                                        b_layers + H, bufE, H, H);
  // h2 = 0.5*tanh(h1 @ W2^T + b2)              [B,H], f16
  gemmsp<1, 4><<<256, blk, 0, stream>>>(bufE, Wlh + (size_t)2 * H * H,
                                        b_layers + 2 * H, bufA, H, H);
  // out = h2 @ W_head^T + b_head               [B,O], f32  (BN=64)
  gemmsp<2, 2><<<256, blk, 0, stream>>>(bufA, Whh, b_head, d_out, O, H);
}